// Round 3
// baseline (359.185 us; speedup 1.0000x reference)
//
#include <hip/hip_runtime.h>
#include <math.h>

// Problem constants
#define M_B   128      // batch
#define N_C   1024     // codes
#define K_D   32000    // feature dim (8*250*16)
#define NTILE 64       // codes per block
#define KCHUNK 1280    // K per block (25 chunks * 1280 = 32000)
#define KSTEP 32       // K staged per LDS step
#define TOPK  5
#define TEMP  0.1f

// ws layout (float offsets):
//   cross [128][1024]   @ 0        (accumulates sum l*c)
//   cnorm [1024]        @ 131072
//   lnorm [128]         @ 132096
//   topidx[128*5] (int) @ 132224
//   topw  [128*5]       @ 132864
#define WS_CROSS  0
#define WS_CNORM  131072
#define WS_LNORM  132096
#define WS_TOPI   132224
#define WS_TOPW   132864
#define WS_ZERO_N 132224   // floats to zero (cross+cnorm+lnorm)

// ---------------------------------------------------------------------------
// Zero the split-K accumulators. (NOT hipMemsetAsync: the harness's graph-
// capture path only supports kernel + hipMemcpyAsync nodes; a memset during
// capture is the prime suspect for the round-1/2 container aborts.)
// ---------------------------------------------------------------------------
__global__ void zero_ws(float* __restrict__ ws) {
  const int i = blockIdx.x * 256 + threadIdx.x;
  if (i < WS_ZERO_N) ws[i] = 0.f;
}

// ---------------------------------------------------------------------------
// Distance GEMM (fp32, split-K). Computes cross[b][j] += sum_k l[b,k]*c[j,k]
// and folds in per-row norm partials (cnorm, lnorm) so the codebook is only
// streamed from HBM once.
// ---------------------------------------------------------------------------
__global__ __launch_bounds__(256) void gemm_dist(
    const float* __restrict__ latent, const float* __restrict__ codebook,
    float* __restrict__ cross, float* __restrict__ cnorm,
    float* __restrict__ lnorm) {
  // +4 pad breaks the power-of-2 LDS stride (bank = (4*kk + m) % 32)
  __shared__ float A_lds[KSTEP][M_B + 4];
  __shared__ float B_lds[KSTEP][NTILE + 4];

  const int tid = threadIdx.x;
  const int nt  = blockIdx.x;   // 0..15 N tile
  const int kc  = blockIdx.y;   // 0..24 K chunk
  const int f4  = tid & 7;      // float4 column within KSTEP
  const int lrow = tid >> 3;    // 0..31

  float acc[8][4];
#pragma unroll
  for (int i = 0; i < 8; i++)
#pragma unroll
    for (int j = 0; j < 4; j++) acc[i][j] = 0.f;
  float lsq[4] = {0.f, 0.f, 0.f, 0.f};
  float csq[2] = {0.f, 0.f};

  const int m0 = (tid >> 4) * 8;   // 8 rows of C-tile per thread
  const int n0 = (tid & 15) * 4;   // 4 cols per thread
  const int kbase = kc * KCHUNK;

  for (int s = 0; s < KCHUNK / KSTEP; ++s) {
    const int k0 = kbase + s * KSTEP + f4 * 4;
    __syncthreads();  // previous step's LDS reads done before overwrite
    // Stage A (latent): 128 rows x 32 k, transposed to [kk][m]
#pragma unroll
    for (int i = 0; i < 4; i++) {
      const int row = lrow + 32 * i;
      const float4 v =
          *reinterpret_cast<const float4*>(latent + (size_t)row * K_D + k0);
      A_lds[f4 * 4 + 0][row] = v.x;
      A_lds[f4 * 4 + 1][row] = v.y;
      A_lds[f4 * 4 + 2][row] = v.z;
      A_lds[f4 * 4 + 3][row] = v.w;
      if (nt == 0) lsq[i] += v.x * v.x + v.y * v.y + v.z * v.z + v.w * v.w;
    }
    // Stage B (codebook tile): 64 rows x 32 k
#pragma unroll
    for (int i = 0; i < 2; i++) {
      const int row = lrow + 32 * i;
      const float4 v = *reinterpret_cast<const float4*>(
          codebook + (size_t)(nt * NTILE + row) * K_D + k0);
      B_lds[f4 * 4 + 0][row] = v.x;
      B_lds[f4 * 4 + 1][row] = v.y;
      B_lds[f4 * 4 + 2][row] = v.z;
      B_lds[f4 * 4 + 3][row] = v.w;
      csq[i] += v.x * v.x + v.y * v.y + v.z * v.z + v.w * v.w;
    }
    __syncthreads();
#pragma unroll
    for (int kk = 0; kk < KSTEP; ++kk) {
      const float4 a0 = *reinterpret_cast<const float4*>(&A_lds[kk][m0]);
      const float4 a1 = *reinterpret_cast<const float4*>(&A_lds[kk][m0 + 4]);
      const float4 bv = *reinterpret_cast<const float4*>(&B_lds[kk][n0]);
      const float a[8] = {a0.x, a0.y, a0.z, a0.w, a1.x, a1.y, a1.z, a1.w};
      const float b[4] = {bv.x, bv.y, bv.z, bv.w};
#pragma unroll
      for (int i = 0; i < 8; i++)
#pragma unroll
        for (int j = 0; j < 4; j++) acc[i][j] += a[i] * b[j];
    }
  }

  // Accumulate split-K partials
#pragma unroll
  for (int i = 0; i < 8; i++)
#pragma unroll
    for (int j = 0; j < 4; j++)
      atomicAdd(cross + (size_t)(m0 + i) * N_C + nt * NTILE + n0 + j,
                acc[i][j]);

  // Norm partial reduction (reuse A_lds as scratch)
  __syncthreads();
  float* scratch = &A_lds[0][0];
  scratch[tid] = csq[0];
  scratch[256 + tid] = csq[1];
  __syncthreads();
  if (tid < 64) {
    const int base = (tid < 32) ? tid * 8 : 256 + (tid - 32) * 8;
    float s = 0.f;
#pragma unroll
    for (int u = 0; u < 8; u++) s += scratch[base + u];
    atomicAdd(cnorm + nt * NTILE + tid, s);
  }
  if (nt == 0) {
    __syncthreads();
#pragma unroll
    for (int i = 0; i < 4; i++) scratch[i * 256 + tid] = lsq[i];
    __syncthreads();
    if (tid < 128) {
      const int i = tid >> 5;
      const int base = i * 256 + (tid & 31) * 8;
      float s = 0.f;
#pragma unroll
      for (int u = 0; u < 8; u++) s += scratch[base + u];
      atomicAdd(lnorm + tid, s);
    }
  }
}

// ---------------------------------------------------------------------------
__global__ void init_usage(const float* __restrict__ usage_in,
                           float* __restrict__ usage_out) {
  const int i = blockIdx.x * 256 + threadIdx.x;
  if (i < N_C) usage_out[i] = usage_in[i];
}

// ---------------------------------------------------------------------------
// Per-latent finalize: d2 -> top-5 (lowest-index tie-break) -> softmax ->
// outputs + usage scatter + ws stash for the quantize gather.
// ---------------------------------------------------------------------------
__global__ __launch_bounds__(256) void finalize(
    const float* __restrict__ cross, const float* __restrict__ cnorm,
    const float* __restrict__ lnorm, float* __restrict__ out_idx,
    float* __restrict__ out_dist, float* __restrict__ out_usage,
    int* __restrict__ topidx, float* __restrict__ topw) {
  const int b = blockIdx.x;
  const int tid = threadIdx.x;
  __shared__ float rv[256];
  __shared__ int ri[256];
  __shared__ float seld[TOPK];
  __shared__ int selj[TOPK];

  float d[4];
  bool used[4];
  const float ln = lnorm[b];
#pragma unroll
  for (int i = 0; i < 4; i++) {
    const int j = i * 256 + tid;
    d[i] = ln + cnorm[j] - 2.f * cross[b * N_C + j];
    used[i] = false;
  }
  for (int it = 0; it < TOPK; ++it) {
    float best = 3.4e38f;
    int bj = N_C;
#pragma unroll
    for (int i = 0; i < 4; i++) {  // ascending i => ascending j, strict <
      const int j = i * 256 + tid; //  => lowest index wins ties
      if (!used[i] && d[i] < best) { best = d[i]; bj = j; }
    }
    rv[tid] = best;
    ri[tid] = bj;
    __syncthreads();
    for (int off = 128; off > 0; off >>= 1) {
      if (tid < off) {
        const float ov = rv[tid + off];
        const int oj = ri[tid + off];
        if (ov < rv[tid] || (ov == rv[tid] && oj < ri[tid])) {
          rv[tid] = ov;
          ri[tid] = oj;
        }
      }
      __syncthreads();
    }
    const int jw = ri[0];
    const float dw = rv[0];
    if (tid == 0) { selj[it] = jw; seld[it] = dw; }
    if ((jw & 255) == tid) used[jw >> 8] = true;  // exclude winner
    __syncthreads();
  }
  if (tid == 0) {
    float dist[TOPK], w[TOPK], wsum = 0.f;
#pragma unroll
    for (int k = 0; k < TOPK; k++) dist[k] = sqrtf(fmaxf(seld[k], 0.f));
#pragma unroll
    for (int k = 0; k < TOPK; k++) {
      w[k] = expf((dist[0] - dist[k]) / TEMP);  // stable: dist[0] is min
      wsum += w[k];
    }
#pragma unroll
    for (int k = 0; k < TOPK; k++) {
      w[k] /= wsum;
      topidx[b * TOPK + k] = selj[k];
      topw[b * TOPK + k] = w[k];
      atomicAdd(out_usage + selj[k], w[k]);
    }
    out_idx[b] = (float)selj[0];   // harness reads flat float32 buffer
    out_dist[b] = dist[0];
  }
}

// ---------------------------------------------------------------------------
// quantized[b,:] = sum_k w[b,k] * codebook[idx[b,k],:]   (float4 gather)
// ---------------------------------------------------------------------------
__global__ __launch_bounds__(256) void quantize(
    const float* __restrict__ codebook, const int* __restrict__ topidx,
    const float* __restrict__ topw, float* __restrict__ out) {
  const int b = blockIdx.y;
  const int dc = blockIdx.x;  // 8 chunks of 1000 float4 = 32000 floats
  const int tid = threadIdx.x;
  int idx[TOPK];
  float w[TOPK];
#pragma unroll
  for (int k = 0; k < TOPK; k++) {
    idx[k] = topidx[b * TOPK + k];
    w[k] = topw[b * TOPK + k];
  }
  const int f4base = dc * 1000;
#pragma unroll
  for (int s = 0; s < 4; s++) {
    const int f = tid + s * 256;
    if (f < 1000) {
      const int dpos = (f4base + f) * 4;
      float4 q = {0.f, 0.f, 0.f, 0.f};
#pragma unroll
      for (int k = 0; k < TOPK; k++) {
        const float4 c = *reinterpret_cast<const float4*>(
            codebook + (size_t)idx[k] * K_D + dpos);
        q.x += w[k] * c.x;
        q.y += w[k] * c.y;
        q.z += w[k] * c.z;
        q.w += w[k] * c.w;
      }
      *reinterpret_cast<float4*>(out + (size_t)b * K_D + dpos) = q;
    }
  }
}

// ---------------------------------------------------------------------------
extern "C" void kernel_launch(void* const* d_in, const int* in_sizes, int n_in,
                              void* d_out, int out_size, void* d_ws,
                              size_t ws_size, hipStream_t stream) {
  const float* latent = (const float*)d_in[0];    // 128*32000
  const float* codebook = (const float*)d_in[1];  // 1024*32000
  const float* usage_in = (const float*)d_in[2];  // 1024

  float* out = (float*)d_out;
  float* quant = out;                  // 4,096,000
  float* out_idx = out + 4096000;      // 128
  float* out_dist = out + 4096128;     // 128
  float* out_usage = out + 4096256;    // 1024

  float* ws = (float*)d_ws;
  float* cross = ws + WS_CROSS;
  float* cnorm = ws + WS_CNORM;
  float* lnorm = ws + WS_LNORM;
  int* topidx = (int*)(ws + WS_TOPI);
  float* topw = ws + WS_TOPW;

  // zero split-K accumulators with a kernel (graph-capture-safe)
  zero_ws<<<(WS_ZERO_N + 255) / 256, 256, 0, stream>>>(ws);

  gemm_dist<<<dim3(16, 25), 256, 0, stream>>>(latent, codebook, cross, cnorm,
                                              lnorm);
  init_usage<<<4, 256, 0, stream>>>(usage_in, out_usage);
  finalize<<<128, 256, 0, stream>>>(cross, cnorm, lnorm, out_idx, out_dist,
                                    out_usage, topidx, topw);
  quantize<<<dim3(8, 128), 256, 0, stream>>>(codebook, topidx, topw, quant);
}

// Round 4
// 347.874 us; speedup vs baseline: 1.0325x; 1.0325x over previous
//
#include <hip/hip_runtime.h>
#include <math.h>

// Problem constants
#define M_B   128      // batch
#define N_C   1024     // codes
#define K_D   32000    // feature dim (8*250*16)
#define NTILE 64       // codes per block
#define KCHUNK 1280    // K per block (16 N-tiles x 25 K-chunks = 400 blocks)
#define KSTEP 64       // bf16 elems staged in LDS per step (20 steps/block)
#define NSTAGE (KCHUNK / KSTEP)
#define LDSK  (KSTEP + 8)   // +8 bf16 (16B) pad: row stride 144B -> <=2-way banks
#define TOPK  5
#define TEMP  0.1f

typedef short bf16x8 __attribute__((ext_vector_type(8)));  // 8 bf16 (4 VGPRs)
typedef float f32x4  __attribute__((ext_vector_type(4)));

// ws layout (float offsets)
#define WS_CROSS  0         // [128][1024]
#define WS_CNORM  131072    // [1024]
#define WS_LNORM  132096    // [128]
#define WS_TOPI   132224    // [128*5] int
#define WS_TOPW   132864    // [128*5]
#define WS_ZERO_N 132224    // floats to zero (cross+cnorm+lnorm)

// ---------------------------------------------------------------------------
// Zero split-K accumulators (kernel, not hipMemsetAsync: capture-safe, proven
// in round 3).
// ---------------------------------------------------------------------------
__global__ void zero_ws(float* __restrict__ ws) {
  const int i = blockIdx.x * 256 + threadIdx.x;
  if (i < WS_ZERO_N) ws[i] = 0.f;
}

// ---------------------------------------------------------------------------
// Split-bf16 MFMA distance GEMM.
//   x = hi + lo exactly, hi = trunc-to-bf16(x), lo = bf16(x - hi) (exact sub,
//   lo truncation error ~2^-18 relative). cross = Ah*Bh + Ah*Bl + Al*Bh.
// Per-row fp32 norms (exact) folded into the same codebook stream.
// ---------------------------------------------------------------------------
__global__ __launch_bounds__(256) void gemm_dist(
    const float* __restrict__ latent, const float* __restrict__ codebook,
    float* __restrict__ cross, float* __restrict__ cnorm,
    float* __restrict__ lnorm) {
  __shared__ alignas(16) unsigned short Ah[M_B][LDSK];
  __shared__ alignas(16) unsigned short Al[M_B][LDSK];
  __shared__ alignas(16) unsigned short Bh[NTILE][LDSK];
  __shared__ alignas(16) unsigned short Bl[NTILE][LDSK];

  const int tid  = threadIdx.x;
  const int nt   = blockIdx.x;   // 0..15 N tile
  const int kc   = blockIdx.y;   // 0..24 K chunk
  const int wave = tid >> 6;     // 0..3: M rows [32w, 32w+32)
  const int lane = tid & 63;
  const int lrow = lane & 15;    // MFMA fragment row/col index
  const int quad = lane >> 4;    // MFMA k-quad

  const int g  = tid >> 4;  // staging row group 0..15 (16 consecutive lanes)
  const int c4 = tid & 15;  // float4 column within KSTEP

  f32x4 acc[2][4];
#pragma unroll
  for (int mt = 0; mt < 2; ++mt)
#pragma unroll
    for (int n = 0; n < 4; ++n) {
      acc[mt][n][0] = 0.f; acc[mt][n][1] = 0.f;
      acc[mt][n][2] = 0.f; acc[mt][n][3] = 0.f;
    }
  float lsq[8] = {0.f, 0.f, 0.f, 0.f, 0.f, 0.f, 0.f, 0.f};
  float csq[4] = {0.f, 0.f, 0.f, 0.f};

  const int kbase = kc * KCHUNK;

  for (int s = 0; s < NSTAGE; ++s) {
    const int k0 = kbase + s * KSTEP + c4 * 4;
    __syncthreads();  // prior step's LDS reads complete before overwrite
    // ---- stage A (latent): 128 rows x 64 k, thread t owns rows g+16i ----
#pragma unroll
    for (int i = 0; i < 8; ++i) {
      const int row = g + 16 * i;
      const float4 v =
          *reinterpret_cast<const float4*>(latent + (size_t)row * K_D + k0);
      const unsigned int ux = __float_as_uint(v.x), uy = __float_as_uint(v.y);
      const unsigned int uz = __float_as_uint(v.z), uw = __float_as_uint(v.w);
      const unsigned int h0 = (ux >> 16) | (uy & 0xFFFF0000u);
      const unsigned int h1 = (uz >> 16) | (uw & 0xFFFF0000u);
      const float lx = v.x - __uint_as_float(ux & 0xFFFF0000u);
      const float ly = v.y - __uint_as_float(uy & 0xFFFF0000u);
      const float lz = v.z - __uint_as_float(uz & 0xFFFF0000u);
      const float lw = v.w - __uint_as_float(uw & 0xFFFF0000u);
      const unsigned int l0 =
          (__float_as_uint(lx) >> 16) | (__float_as_uint(ly) & 0xFFFF0000u);
      const unsigned int l1 =
          (__float_as_uint(lz) >> 16) | (__float_as_uint(lw) & 0xFFFF0000u);
      *reinterpret_cast<uint2*>(&Ah[row][c4 * 4]) = make_uint2(h0, h1);
      *reinterpret_cast<uint2*>(&Al[row][c4 * 4]) = make_uint2(l0, l1);
      if (nt == 0) lsq[i] += v.x * v.x + v.y * v.y + v.z * v.z + v.w * v.w;
    }
    // ---- stage B (codebook): 64 rows x 64 k, thread t owns rows g+16i ----
#pragma unroll
    for (int i = 0; i < 4; ++i) {
      const int row = g + 16 * i;
      const float4 v = *reinterpret_cast<const float4*>(
          codebook + (size_t)(nt * NTILE + row) * K_D + k0);
      const unsigned int ux = __float_as_uint(v.x), uy = __float_as_uint(v.y);
      const unsigned int uz = __float_as_uint(v.z), uw = __float_as_uint(v.w);
      const unsigned int h0 = (ux >> 16) | (uy & 0xFFFF0000u);
      const unsigned int h1 = (uz >> 16) | (uw & 0xFFFF0000u);
      const float lx = v.x - __uint_as_float(ux & 0xFFFF0000u);
      const float ly = v.y - __uint_as_float(uy & 0xFFFF0000u);
      const float lz = v.z - __uint_as_float(uz & 0xFFFF0000u);
      const float lw = v.w - __uint_as_float(uw & 0xFFFF0000u);
      const unsigned int l0 =
          (__float_as_uint(lx) >> 16) | (__float_as_uint(ly) & 0xFFFF0000u);
      const unsigned int l1 =
          (__float_as_uint(lz) >> 16) | (__float_as_uint(lw) & 0xFFFF0000u);
      *reinterpret_cast<uint2*>(&Bh[row][c4 * 4]) = make_uint2(h0, h1);
      *reinterpret_cast<uint2*>(&Bl[row][c4 * 4]) = make_uint2(l0, l1);
      csq[i] += v.x * v.x + v.y * v.y + v.z * v.z + v.w * v.w;
    }
    __syncthreads();
    // ---- MFMA: wave w does M [32w,32w+32) x N [0,64), two 32-k halves ----
#pragma unroll
    for (int kh = 0; kh < 2; ++kh) {
      const int kf = kh * 32 + quad * 8;  // A[m=lane&15][k=quad*8+j] layout
      bf16x8 ah[2], al[2], bh[4], bl[4];
#pragma unroll
      for (int mt = 0; mt < 2; ++mt) {
        const int m = wave * 32 + mt * 16 + lrow;
        ah[mt] = *reinterpret_cast<const bf16x8*>(&Ah[m][kf]);
        al[mt] = *reinterpret_cast<const bf16x8*>(&Al[m][kf]);
      }
#pragma unroll
      for (int n = 0; n < 4; ++n) {
        const int nr = n * 16 + lrow;
        bh[n] = *reinterpret_cast<const bf16x8*>(&Bh[nr][kf]);
        bl[n] = *reinterpret_cast<const bf16x8*>(&Bl[nr][kf]);
      }
#pragma unroll
      for (int mt = 0; mt < 2; ++mt)
#pragma unroll
        for (int n = 0; n < 4; ++n) {
          acc[mt][n] = __builtin_amdgcn_mfma_f32_16x16x32_bf16(
              ah[mt], bh[n], acc[mt][n], 0, 0, 0);
          acc[mt][n] = __builtin_amdgcn_mfma_f32_16x16x32_bf16(
              ah[mt], bl[n], acc[mt][n], 0, 0, 0);
          acc[mt][n] = __builtin_amdgcn_mfma_f32_16x16x32_bf16(
              al[mt], bh[n], acc[mt][n], 0, 0, 0);
        }
    }
  }

  // ---- split-K accumulate: C/D layout col=lane&15, row=quad*4+reg (m89) ----
#pragma unroll
  for (int mt = 0; mt < 2; ++mt) {
    const int mrow0 = wave * 32 + mt * 16 + quad * 4;
#pragma unroll
    for (int n = 0; n < 4; ++n) {
      const int col = nt * NTILE + n * 16 + lrow;
#pragma unroll
      for (int r = 0; r < 4; ++r)
        atomicAdd(cross + (size_t)(mrow0 + r) * N_C + col, acc[mt][n][r]);
    }
  }

  // ---- norms: reduce within 16-lane groups (each group owns fixed rows) ----
#pragma unroll
  for (int off = 8; off > 0; off >>= 1) {
#pragma unroll
    for (int i = 0; i < 4; ++i) csq[i] += __shfl_down(csq[i], off, 16);
#pragma unroll
    for (int i = 0; i < 8; ++i) lsq[i] += __shfl_down(lsq[i], off, 16);
  }
  if ((tid & 15) == 0) {
#pragma unroll
    for (int i = 0; i < 4; ++i)
      atomicAdd(cnorm + nt * NTILE + g + 16 * i, csq[i]);
    if (nt == 0) {
#pragma unroll
      for (int i = 0; i < 8; ++i) atomicAdd(lnorm + g + 16 * i, lsq[i]);
    }
  }
}

// ---------------------------------------------------------------------------
__global__ void init_usage(const float* __restrict__ usage_in,
                           float* __restrict__ usage_out) {
  const int i = blockIdx.x * 256 + threadIdx.x;
  if (i < N_C) usage_out[i] = usage_in[i];
}

// ---------------------------------------------------------------------------
// Per-latent finalize: d2 -> top-5 (lowest-index tie-break) -> softmax ->
// outputs + usage scatter + ws stash for the quantize gather.
// ---------------------------------------------------------------------------
__global__ __launch_bounds__(256) void finalize(
    const float* __restrict__ cross, const float* __restrict__ cnorm,
    const float* __restrict__ lnorm, float* __restrict__ out_idx,
    float* __restrict__ out_dist, float* __restrict__ out_usage,
    int* __restrict__ topidx, float* __restrict__ topw) {
  const int b = blockIdx.x;
  const int tid = threadIdx.x;
  __shared__ float rv[256];
  __shared__ int ri[256];
  __shared__ float seld[TOPK];
  __shared__ int selj[TOPK];

  float d[4];
  bool used[4];
  const float ln = lnorm[b];
#pragma unroll
  for (int i = 0; i < 4; i++) {
    const int j = i * 256 + tid;
    d[i] = ln + cnorm[j] - 2.f * cross[b * N_C + j];
    used[i] = false;
  }
  for (int it = 0; it < TOPK; ++it) {
    float best = 3.4e38f;
    int bj = N_C;
#pragma unroll
    for (int i = 0; i < 4; i++) {  // ascending j + strict < => lowest idx wins
      const int j = i * 256 + tid;
      if (!used[i] && d[i] < best) { best = d[i]; bj = j; }
    }
    rv[tid] = best;
    ri[tid] = bj;
    __syncthreads();
    for (int off = 128; off > 0; off >>= 1) {
      if (tid < off) {
        const float ov = rv[tid + off];
        const int oj = ri[tid + off];
        if (ov < rv[tid] || (ov == rv[tid] && oj < ri[tid])) {
          rv[tid] = ov;
          ri[tid] = oj;
        }
      }
      __syncthreads();
    }
    const int jw = ri[0];
    const float dw = rv[0];
    if (tid == 0) { selj[it] = jw; seld[it] = dw; }
    if ((jw & 255) == tid) used[jw >> 8] = true;  // exclude winner
    __syncthreads();
  }
  if (tid == 0) {
    float dist[TOPK], w[TOPK], wsum = 0.f;
#pragma unroll
    for (int k = 0; k < TOPK; k++) dist[k] = sqrtf(fmaxf(seld[k], 0.f));
#pragma unroll
    for (int k = 0; k < TOPK; k++) {
      w[k] = expf((dist[0] - dist[k]) / TEMP);  // stable: dist[0] is min
      wsum += w[k];
    }
#pragma unroll
    for (int k = 0; k < TOPK; k++) {
      w[k] /= wsum;
      topidx[b * TOPK + k] = selj[k];
      topw[b * TOPK + k] = w[k];
      atomicAdd(out_usage + selj[k], w[k]);
    }
    out_idx[b] = (float)selj[0];  // harness reads flat float32 buffer
    out_dist[b] = dist[0];
  }
}

// ---------------------------------------------------------------------------
// quantized[b,:] = sum_k w[b,k] * codebook[idx[b,k],:]   (float4 gather)
// ---------------------------------------------------------------------------
__global__ __launch_bounds__(256) void quantize(
    const float* __restrict__ codebook, const int* __restrict__ topidx,
    const float* __restrict__ topw, float* __restrict__ out) {
  const int b = blockIdx.y;
  const int dc = blockIdx.x;  // 8 chunks of 1000 float4 = 32000 floats
  const int tid = threadIdx.x;
  int idx[TOPK];
  float w[TOPK];
#pragma unroll
  for (int k = 0; k < TOPK; k++) {
    idx[k] = topidx[b * TOPK + k];
    w[k] = topw[b * TOPK + k];
  }
  const int f4base = dc * 1000;
#pragma unroll
  for (int s = 0; s < 4; s++) {
    const int f = tid + s * 256;
    if (f < 1000) {
      const int dpos = (f4base + f) * 4;
      float4 q = {0.f, 0.f, 0.f, 0.f};
#pragma unroll
      for (int k = 0; k < TOPK; k++) {
        const float4 c = *reinterpret_cast<const float4*>(
            codebook + (size_t)idx[k] * K_D + dpos);
        q.x += w[k] * c.x;
        q.y += w[k] * c.y;
        q.z += w[k] * c.z;
        q.w += w[k] * c.w;
      }
      *reinterpret_cast<float4*>(out + (size_t)b * K_D + dpos) = q;
    }
  }
}

// ---------------------------------------------------------------------------
extern "C" void kernel_launch(void* const* d_in, const int* in_sizes, int n_in,
                              void* d_out, int out_size, void* d_ws,
                              size_t ws_size, hipStream_t stream) {
  const float* latent = (const float*)d_in[0];    // 128*32000
  const float* codebook = (const float*)d_in[1];  // 1024*32000
  const float* usage_in = (const float*)d_in[2];  // 1024

  float* out = (float*)d_out;
  float* quant = out;                // 4,096,000
  float* out_idx = out + 4096000;    // 128
  float* out_dist = out + 4096128;   // 128
  float* out_usage = out + 4096256;  // 1024

  float* ws = (float*)d_ws;
  float* cross = ws + WS_CROSS;
  float* cnorm = ws + WS_CNORM;
  float* lnorm = ws + WS_LNORM;
  int* topidx = (int*)(ws + WS_TOPI);
  float* topw = ws + WS_TOPW;

  zero_ws<<<(WS_ZERO_N + 255) / 256, 256, 0, stream>>>(ws);
  gemm_dist<<<dim3(16, 25), 256, 0, stream>>>(latent, codebook, cross, cnorm,
                                              lnorm);
  init_usage<<<4, 256, 0, stream>>>(usage_in, out_usage);
  finalize<<<128, 256, 0, stream>>>(cross, cnorm, lnorm, out_idx, out_dist,
                                    out_usage, topidx, topw);
  quantize<<<dim3(8, 128), 256, 0, stream>>>(codebook, topidx, topw, quant);
}

// Round 5
// 265.722 us; speedup vs baseline: 1.3517x; 1.3092x over previous
//
#include <hip/hip_runtime.h>
#include <math.h>

// Problem constants
#define M_B   128      // batch
#define N_C   1024     // codes
#define K_D   32000    // feature dim (8*250*16)
#define NTILE 64       // codes per block
#define KCHUNK 640     // K per block (16 N-tiles x 50 K-chunks = 800 blocks)
#define KSTEP 64       // bf16 elems staged in LDS per step (10 steps/block)
#define NSTAGE (KCHUNK / KSTEP)
#define LDSK  (KSTEP + 8)   // +8 bf16 (16B) pad: row stride 144B, balanced banks
#define TOPK  5
#define TEMP  0.1f

typedef short bf16x8 __attribute__((ext_vector_type(8)));  // 8 bf16 (4 VGPRs)
typedef float f32x4  __attribute__((ext_vector_type(4)));

// ws layout (float offsets)
#define WS_CROSS  0         // [128][1024]
#define WS_CNORM  131072    // [1024]
#define WS_LNORM  132096    // [128]
#define WS_TOPI   132224    // [128*5] int
#define WS_TOPW   132864    // [128*5]
#define WS_ZERO_N 132224    // floats to zero (cross+cnorm+lnorm)

// ---------------------------------------------------------------------------
// prep: zero split-K accumulators + copy usage (kernel, not hipMemsetAsync —
// capture-safe, proven round 3; merged to save one launch).
// ---------------------------------------------------------------------------
__global__ void prep(float* __restrict__ ws, const float* __restrict__ usage_in,
                     float* __restrict__ usage_out) {
  const int i = blockIdx.x * 256 + threadIdx.x;
  if (i < WS_ZERO_N) ws[i] = 0.f;
  if (i < N_C) usage_out[i] = usage_in[i];
}

// fp32x8 -> bf16x8 hi plane + lo plane (exact split: x = hi + lo + ~2^-18 rel)
__device__ inline void cvt8(const float4 p0, const float4 p1, uint4& hi,
                            uint4& lo) {
  const unsigned int u0 = __float_as_uint(p0.x), u1 = __float_as_uint(p0.y);
  const unsigned int u2 = __float_as_uint(p0.z), u3 = __float_as_uint(p0.w);
  const unsigned int u4 = __float_as_uint(p1.x), u5 = __float_as_uint(p1.y);
  const unsigned int u6 = __float_as_uint(p1.z), u7 = __float_as_uint(p1.w);
  hi.x = (u0 >> 16) | (u1 & 0xFFFF0000u);
  hi.y = (u2 >> 16) | (u3 & 0xFFFF0000u);
  hi.z = (u4 >> 16) | (u5 & 0xFFFF0000u);
  hi.w = (u6 >> 16) | (u7 & 0xFFFF0000u);
  const float l0 = p0.x - __uint_as_float(u0 & 0xFFFF0000u);
  const float l1 = p0.y - __uint_as_float(u1 & 0xFFFF0000u);
  const float l2 = p0.z - __uint_as_float(u2 & 0xFFFF0000u);
  const float l3 = p0.w - __uint_as_float(u3 & 0xFFFF0000u);
  const float l4 = p1.x - __uint_as_float(u4 & 0xFFFF0000u);
  const float l5 = p1.y - __uint_as_float(u5 & 0xFFFF0000u);
  const float l6 = p1.z - __uint_as_float(u6 & 0xFFFF0000u);
  const float l7 = p1.w - __uint_as_float(u7 & 0xFFFF0000u);
  lo.x = (__float_as_uint(l0) >> 16) | (__float_as_uint(l1) & 0xFFFF0000u);
  lo.y = (__float_as_uint(l2) >> 16) | (__float_as_uint(l3) & 0xFFFF0000u);
  lo.z = (__float_as_uint(l4) >> 16) | (__float_as_uint(l5) & 0xFFFF0000u);
  lo.w = (__float_as_uint(l6) >> 16) | (__float_as_uint(l7) & 0xFFFF0000u);
}

// ---------------------------------------------------------------------------
// Split-bf16 MFMA distance GEMM: cross = Ah*Bh + Ah*Bl + Al*Bh (fp32 acc).
// B (codebook) staged through LDS; A (latent, L3-hot) loaded straight into
// register fragments per wave -> LDS 18.4 KB/block, grid 800 blocks (~3/CU).
// ---------------------------------------------------------------------------
__global__ __launch_bounds__(256, 3) void gemm_dist(
    const float* __restrict__ latent, const float* __restrict__ codebook,
    float* __restrict__ cross, float* __restrict__ cnorm,
    float* __restrict__ lnorm) {
  __shared__ alignas(16) unsigned short Bh[NTILE][LDSK];
  __shared__ alignas(16) unsigned short Bl[NTILE][LDSK];

  const int tid  = threadIdx.x;
  const int nt   = blockIdx.x;   // 0..15 N tile
  const int kc   = blockIdx.y;   // 0..49 K chunk
  const int wave = tid >> 6;     // 0..3: M rows [32w, 32w+32)
  const int lane = tid & 63;
  const int lrow = lane & 15;    // MFMA fragment row/col index
  const int quad = lane >> 4;    // MFMA k-quad

  const int brow = tid >> 2;        // staging: B row 0..63
  const int bcol = (tid & 3) * 16;  // 16 k-elems (2 float4) per thread

  f32x4 acc[2][4];
#pragma unroll
  for (int mt = 0; mt < 2; ++mt)
#pragma unroll
    for (int n = 0; n < 4; ++n) {
      acc[mt][n][0] = 0.f; acc[mt][n][1] = 0.f;
      acc[mt][n][2] = 0.f; acc[mt][n][3] = 0.f;
    }
  float lsq[2] = {0.f, 0.f};
  float csq = 0.f;

  const int kbase = kc * KCHUNK;
  const float* browp = codebook + (size_t)(nt * NTILE + brow) * K_D;

  for (int s = 0; s < NSTAGE; ++s) {
    const int k0 = kbase + s * KSTEP;
    __syncthreads();  // prior step's fragment reads complete before overwrite
    // ---- stage B (codebook) 64x64 into LDS hi/lo planes ----
#pragma unroll
    for (int u = 0; u < 2; ++u) {
      const int kk = k0 + bcol + u * 8;
      const float4 p0 = *reinterpret_cast<const float4*>(browp + kk);
      const float4 p1 = *reinterpret_cast<const float4*>(browp + kk + 4);
      uint4 hi, lo;
      cvt8(p0, p1, hi, lo);
      *reinterpret_cast<uint4*>(&Bh[brow][bcol + u * 8]) = hi;
      *reinterpret_cast<uint4*>(&Bl[brow][bcol + u * 8]) = lo;
      csq += p0.x * p0.x + p0.y * p0.y + p0.z * p0.z + p0.w * p0.w +
             p1.x * p1.x + p1.y * p1.y + p1.z * p1.z + p1.w * p1.w;
    }
    // ---- A fragments straight from global (layout A[m=lane&15][k=quad*8+j])
    bf16x8 ah[2][2], al[2][2];
#pragma unroll
    for (int mt = 0; mt < 2; ++mt) {
      const float* arow =
          latent + (size_t)(wave * 32 + mt * 16 + lrow) * K_D + k0 + quad * 8;
#pragma unroll
      for (int kh = 0; kh < 2; ++kh) {
        const float4 p0 = *reinterpret_cast<const float4*>(arow + kh * 32);
        const float4 p1 = *reinterpret_cast<const float4*>(arow + kh * 32 + 4);
        uint4 hi, lo;
        cvt8(p0, p1, hi, lo);
        ah[mt][kh] = *reinterpret_cast<bf16x8*>(&hi);
        al[mt][kh] = *reinterpret_cast<bf16x8*>(&lo);
        if (nt == 0)
          lsq[mt] += p0.x * p0.x + p0.y * p0.y + p0.z * p0.z + p0.w * p0.w +
                     p1.x * p1.x + p1.y * p1.y + p1.z * p1.z + p1.w * p1.w;
      }
    }
    __syncthreads();  // B visible
    // ---- MFMA: wave does M[32w,32w+32) x N[0,64) ----
#pragma unroll
    for (int kh = 0; kh < 2; ++kh) {
      const int kf = kh * 32 + quad * 8;
#pragma unroll
      for (int n = 0; n < 4; ++n) {
        const bf16x8 bh =
            *reinterpret_cast<const bf16x8*>(&Bh[n * 16 + lrow][kf]);
        const bf16x8 bl =
            *reinterpret_cast<const bf16x8*>(&Bl[n * 16 + lrow][kf]);
#pragma unroll
        for (int mt = 0; mt < 2; ++mt) {
          acc[mt][n] = __builtin_amdgcn_mfma_f32_16x16x32_bf16(
              ah[mt][kh], bh, acc[mt][n], 0, 0, 0);
          acc[mt][n] = __builtin_amdgcn_mfma_f32_16x16x32_bf16(
              ah[mt][kh], bl, acc[mt][n], 0, 0, 0);
          acc[mt][n] = __builtin_amdgcn_mfma_f32_16x16x32_bf16(
              al[mt][kh], bh, acc[mt][n], 0, 0, 0);
        }
      }
    }
  }

  // ---- split-K accumulate: C/D layout col=lane&15, row=quad*4+reg (m89) ----
#pragma unroll
  for (int mt = 0; mt < 2; ++mt) {
    const int mrow0 = wave * 32 + mt * 16 + quad * 4;
#pragma unroll
    for (int n = 0; n < 4; ++n) {
      const int col = nt * NTILE + n * 16 + lrow;
#pragma unroll
      for (int r = 0; r < 4; ++r)
        atomicAdd(cross + (size_t)(mrow0 + r) * N_C + col, acc[mt][n][r]);
    }
  }

  // ---- codebook norms: 4 threads (tid&3) share row brow ----
  csq += __shfl_down(csq, 2, 4);
  csq += __shfl_down(csq, 1, 4);
  if ((tid & 3) == 0) atomicAdd(cnorm + nt * NTILE + brow, csq);
  // ---- latent norms (nt==0 blocks cover all K): reduce over quads ----
  if (nt == 0) {
#pragma unroll
    for (int mt = 0; mt < 2; ++mt) {
      lsq[mt] += __shfl_down(lsq[mt], 32);
      lsq[mt] += __shfl_down(lsq[mt], 16);
      if (lane < 16) atomicAdd(lnorm + wave * 32 + mt * 16 + lane, lsq[mt]);
    }
  }
}

// ---------------------------------------------------------------------------
// Per-latent finalize: d2 -> top-5 (lowest-index tie-break) -> softmax ->
// outputs + usage scatter + ws stash for the quantize gather.
// ---------------------------------------------------------------------------
__global__ __launch_bounds__(256) void finalize(
    const float* __restrict__ cross, const float* __restrict__ cnorm,
    const float* __restrict__ lnorm, float* __restrict__ out_idx,
    float* __restrict__ out_dist, float* __restrict__ out_usage,
    int* __restrict__ topidx, float* __restrict__ topw) {
  const int b = blockIdx.x;
  const int tid = threadIdx.x;
  __shared__ float rv[256];
  __shared__ int ri[256];
  __shared__ float seld[TOPK];
  __shared__ int selj[TOPK];

  float d[4];
  bool used[4];
  const float ln = lnorm[b];
#pragma unroll
  for (int i = 0; i < 4; i++) {
    const int j = i * 256 + tid;
    d[i] = ln + cnorm[j] - 2.f * cross[b * N_C + j];
    used[i] = false;
  }
  for (int it = 0; it < TOPK; ++it) {
    float best = 3.4e38f;
    int bj = N_C;
#pragma unroll
    for (int i = 0; i < 4; i++) {  // ascending j + strict < => lowest idx wins
      const int j = i * 256 + tid;
      if (!used[i] && d[i] < best) { best = d[i]; bj = j; }
    }
    rv[tid] = best;
    ri[tid] = bj;
    __syncthreads();
    for (int off = 128; off > 0; off >>= 1) {
      if (tid < off) {
        const float ov = rv[tid + off];
        const int oj = ri[tid + off];
        if (ov < rv[tid] || (ov == rv[tid] && oj < ri[tid])) {
          rv[tid] = ov;
          ri[tid] = oj;
        }
      }
      __syncthreads();
    }
    const int jw = ri[0];
    const float dw = rv[0];
    if (tid == 0) { selj[it] = jw; seld[it] = dw; }
    if ((jw & 255) == tid) used[jw >> 8] = true;  // exclude winner
    __syncthreads();
  }
  if (tid == 0) {
    float dist[TOPK], w[TOPK], wsum = 0.f;
#pragma unroll
    for (int k = 0; k < TOPK; k++) dist[k] = sqrtf(fmaxf(seld[k], 0.f));
#pragma unroll
    for (int k = 0; k < TOPK; k++) {
      w[k] = expf((dist[0] - dist[k]) / TEMP);  // stable: dist[0] is min
      wsum += w[k];
    }
#pragma unroll
    for (int k = 0; k < TOPK; k++) {
      w[k] /= wsum;
      topidx[b * TOPK + k] = selj[k];
      topw[b * TOPK + k] = w[k];
      atomicAdd(out_usage + selj[k], w[k]);
    }
    out_idx[b] = (float)selj[0];  // harness reads flat float32 buffer
    out_dist[b] = dist[0];
  }
}

// ---------------------------------------------------------------------------
// quantized[b,:] = sum_k w[b,k] * codebook[idx[b,k],:]   (float4 gather)
// ---------------------------------------------------------------------------
__global__ __launch_bounds__(256) void quantize(
    const float* __restrict__ codebook, const int* __restrict__ topidx,
    const float* __restrict__ topw, float* __restrict__ out) {
  const int b = blockIdx.y;
  const int dc = blockIdx.x;  // 8 chunks of 1000 float4 = 32000 floats
  const int tid = threadIdx.x;
  int idx[TOPK];
  float w[TOPK];
#pragma unroll
  for (int k = 0; k < TOPK; k++) {
    idx[k] = topidx[b * TOPK + k];
    w[k] = topw[b * TOPK + k];
  }
  const int f4base = dc * 1000;
#pragma unroll
  for (int s = 0; s < 4; s++) {
    const int f = tid + s * 256;
    if (f < 1000) {
      const int dpos = (f4base + f) * 4;
      float4 q = {0.f, 0.f, 0.f, 0.f};
#pragma unroll
      for (int k = 0; k < TOPK; k++) {
        const float4 c = *reinterpret_cast<const float4*>(
            codebook + (size_t)idx[k] * K_D + dpos);
        q.x += w[k] * c.x;
        q.y += w[k] * c.y;
        q.z += w[k] * c.z;
        q.w += w[k] * c.w;
      }
      *reinterpret_cast<float4*>(out + (size_t)b * K_D + dpos) = q;
    }
  }
}

// ---------------------------------------------------------------------------
extern "C" void kernel_launch(void* const* d_in, const int* in_sizes, int n_in,
                              void* d_out, int out_size, void* d_ws,
                              size_t ws_size, hipStream_t stream) {
  const float* latent = (const float*)d_in[0];    // 128*32000
  const float* codebook = (const float*)d_in[1];  // 1024*32000
  const float* usage_in = (const float*)d_in[2];  // 1024

  float* out = (float*)d_out;
  float* quant = out;                // 4,096,000
  float* out_idx = out + 4096000;    // 128
  float* out_dist = out + 4096128;   // 128
  float* out_usage = out + 4096256;  // 1024

  float* ws = (float*)d_ws;
  float* cross = ws + WS_CROSS;
  float* cnorm = ws + WS_CNORM;
  float* lnorm = ws + WS_LNORM;
  int* topidx = (int*)(ws + WS_TOPI);
  float* topw = ws + WS_TOPW;

  prep<<<(WS_ZERO_N + 255) / 256, 256, 0, stream>>>(ws, usage_in, out_usage);
  gemm_dist<<<dim3(16, 50), 256, 0, stream>>>(latent, codebook, cross, cnorm,
                                              lnorm);
  finalize<<<128, 256, 0, stream>>>(cross, cnorm, lnorm, out_idx, out_dist,
                                    out_usage, topidx, topw);
  quantize<<<dim3(8, 128), 256, 0, stream>>>(codebook, topidx, topw, quant);
}